// Round 10
// baseline (523.348 us; speedup 1.0000x reference)
//
#include <hip/hip_runtime.h>
#include <hip/hip_bf16.h>

// CausalSelfAttention: B=4 T=2048 C=1024 H=16 D=64
// ws layout (bytes):
//   xb   @ 0         : x as bf16           [8192][1024]   16 MB
//   wat  @ 16777216  : w_attn^T bf16       [3072][1024]    6 MB
//   wpt  @ 23068672  : w_proj^T bf16       [1024][1024]    2 MB
//   Qb   @ 25165824  : Q bf16 (pre-scaled by 0.125*log2e) [B,H,T,D] 16 MB
//   Kb   @ 41943040  : K bf16  [B,H,T,D]                  16 MB
//   V4   @ 58720256  : V fragment-tiled bf16 [bh][kt][kb][mt][lane][4] 16 MB
//   Ob   @ 75497472  : attn out bf16 [8192][1024]         16 MB
//
// R21: (a) flash: single-wave blocks (4096 x 64thr), bid -> (bh=bid&63,
// c=63-(bid>>6)): each CU's 16 chunks step c by -4 -> per-CU work equalized
// by construction (R20 post-mortem: 20x per-block imbalance -> 26% occupancy
// tail). K double-buffered in registers one iteration ahead (static named
// sets, 2-step unrolled loop); V4 loads hoisted to compute top (covered by
// QK+softmax). V4 coalesced layout kept (R20: one 512B segment/instr).
// No LDS/barriers. __launch_bounds__(64,4) = 4 waves/SIMD.
// (b) qkv: revert to R16 measured-best (80.8us) 256^2 reg-prefetch kernel,
// V-branch swapped to V4 layout (t0=(mb+8g)&2047, mb%4==0; same b64 width).

typedef float f32x4 __attribute__((ext_vector_type(4)));
typedef float f32x16 __attribute__((ext_vector_type(16)));
typedef short short8 __attribute__((ext_vector_type(8)));
typedef short short4v __attribute__((ext_vector_type(4)));

__device__ __forceinline__ short f2bf(float f) {
  union { __hip_bfloat16 h; short s; } u;
  u.h = __float2bfloat16(f);
  return u.s;
}

__device__ __forceinline__ void gl_lds16(const void* g, void* l) {
  __builtin_amdgcn_global_load_lds(
      (const __attribute__((address_space(1))) void*)g,
      (__attribute__((address_space(3))) void*)l, 16, 0, 0);
}

// ---------------- fused prep: x cvt + w_attn^T + w_proj^T -------------------
__global__ void prep(const float* __restrict__ x, const float* __restrict__ wa,
                     const float* __restrict__ wp, short* __restrict__ xb,
                     short* __restrict__ wat, short* __restrict__ wpt) {
  const int bid = blockIdx.x, tid = threadIdx.x;
  if (bid < 8192) {
    int i = (bid * 256 + tid) * 4;
    float4 v = *(const float4*)(x + i);
    short4v o;
    o[0] = f2bf(v.x); o[1] = f2bf(v.y); o[2] = f2bf(v.z); o[3] = f2bf(v.w);
    *(short4v*)(xb + i) = o;
    return;
  }
  __shared__ float tile[32][33];
  const float* in;
  short* out;
  int N, bx, by;
  if (bid < 11264) {
    int t = bid - 8192;
    in = wa; out = wat; N = 3072; bx = t % 96; by = t / 96;
  } else {
    int t = bid - 11264;
    in = wp; out = wpt; N = 1024; bx = t & 31; by = t >> 5;
  }
  int tx = tid & 31, ty = tid >> 5;  // 32 x 8
  int x0 = bx * 32, y0 = by * 32;
#pragma unroll
  for (int i = 0; i < 32; i += 8)
    tile[ty + i][tx] = in[(size_t)(y0 + ty + i) * N + x0 + tx];
  __syncthreads();
#pragma unroll
  for (int i = 0; i < 32; i += 8)
    out[(size_t)(x0 + ty + i) * 1024 + y0 + tx] = f2bf(tile[tx][ty + i]);
}

// ------ proj GEMM core: 128x128, BK=32, 4 waves, DBUF LDS, 1 barrier/kt ----
#define GEMM_BODY(A_, Bt_)                                                        \
  __shared__ __align__(16) short As[2][128 * 32];                                 \
  __shared__ __align__(16) short Bs[2][128 * 32];                                 \
  const int tid = threadIdx.x;                                                    \
  const int wv = tid >> 6;                                                        \
  const int wr = wv >> 1, wc = wv & 1;                                            \
  const int col = tid & 31, khalf = (tid >> 5) & 1;                               \
  const int m0 = blockIdx.y * 128, n0 = blockIdx.x * 128;                         \
  const int cc0 = tid, cc1 = tid + 256;                                           \
  const int row0 = cc0 >> 2, part0 = ((cc0 & 3) - ((cc0 >> 3) & 3)) & 3;          \
  const int row1 = cc1 >> 2, part1 = ((cc1 & 3) - ((cc1 >> 3) & 3)) & 3;          \
  const size_t ga0 = (size_t)(m0 + row0) * 1024 + part0 * 8;                      \
  const size_t ga1 = (size_t)(m0 + row1) * 1024 + part1 * 8;                      \
  const size_t gb0 = (size_t)(n0 + row0) * 1024 + part0 * 8;                      \
  const size_t gb1 = (size_t)(n0 + row1) * 1024 + part1 * 8;                      \
  f32x16 acc[2][2];                                                               \
  _Pragma("unroll") for (int i = 0; i < 2; ++i)                                   \
      _Pragma("unroll") for (int j = 0; j < 2; ++j)                               \
          acc[i][j] = (f32x16)(0.f);                                              \
  gl_lds16(A_ + ga0, (char*)As[0] + cc0 * 16);                                    \
  gl_lds16(A_ + ga1, (char*)As[0] + cc1 * 16);                                    \
  gl_lds16(Bt_ + gb0, (char*)Bs[0] + cc0 * 16);                                   \
  gl_lds16(Bt_ + gb1, (char*)Bs[0] + cc1 * 16);                                   \
  __syncthreads();                                                                \
  for (int kt = 0; kt < 32; ++kt) {                                               \
    if (kt + 1 < 32) {                                                            \
      const int k0 = (kt + 1) * 32;                                               \
      char* Ad = (char*)As[(kt + 1) & 1];                                         \
      char* Bd = (char*)Bs[(kt + 1) & 1];                                         \
      gl_lds16(A_ + ga0 + k0, Ad + cc0 * 16);                                     \
      gl_lds16(A_ + ga1 + k0, Ad + cc1 * 16);                                     \
      gl_lds16(Bt_ + gb0 + k0, Bd + cc0 * 16);                                    \
      gl_lds16(Bt_ + gb1 + k0, Bd + cc1 * 16);                                    \
    }                                                                             \
    const short* Ac = As[kt & 1];                                                 \
    const short* Bc = Bs[kt & 1];                                                 \
    short8 af[2][2], bf[2][2];                                                    \
    _Pragma("unroll") for (int i = 0; i < 2; ++i)                                 \
        _Pragma("unroll") for (int s = 0; s < 2; ++s) {                           \
          int pa = s * 2 + khalf;                                                 \
          int ra = wr * 64 + i * 32 + col;                                        \
          int rb = wc * 64 + i * 32 + col;                                        \
          af[i][s] = *(const short8*)&Ac[(ra * 4 + ((pa + (ra >> 1)) & 3)) * 8];  \
          bf[i][s] = *(const short8*)&Bc[(rb * 4 + ((pa + (rb >> 1)) & 3)) * 8];  \
        }                                                                         \
    _Pragma("unroll") for (int s = 0; s < 2; ++s)                                 \
        _Pragma("unroll") for (int i = 0; i < 2; ++i)                             \
            _Pragma("unroll") for (int j = 0; j < 2; ++j)                         \
                acc[i][j] = __builtin_amdgcn_mfma_f32_32x32x16_bf16(              \
                    af[i][s], bf[j][s], acc[i][j], 0, 0, 0);                      \
    __syncthreads();                                                              \
  }

__global__ __launch_bounds__(256, 2) void gemm_proj(
    const short* __restrict__ A, const short* __restrict__ Bt,
    const float* __restrict__ bias, float* __restrict__ out) {
  GEMM_BODY(A, Bt)
  const int rhalf = khalf * 4;
#pragma unroll
  for (int i = 0; i < 2; ++i) {
#pragma unroll
    for (int j = 0; j < 2; ++j) {
      int n = n0 + wc * 64 + j * 32 + col;
      float bv = bias[n];
      int mb = m0 + wr * 64 + i * 32 + rhalf;
#pragma unroll
      for (int a = 0; a < 16; ++a) {
        int m = mb + (a & 3) + 8 * (a >> 2);
        out[(size_t)m * 1024 + n] = acc[i][j][a] + bv;
      }
    }
  }
}

// ------------- QKV GEMM: R16 (256x256, BK=64, reg-prefetch, 2 barriers/kt) -
#define BARRIER() asm volatile("s_barrier" ::: "memory")
#define VMC(N) asm volatile("s_waitcnt vmcnt(" #N ")" ::: "memory")

#define STG(KT, S, SRC, LB)                                                \
  if ((KT) < 16) {                                                         \
    char* db_ = (char*)(LB) + (((KT) & 1) ? 32768 : 0) + ((S) * 16384);    \
    const short* sb_ = (SRC) + (KT) * 64 + (S) * 32;                       \
    gl_lds16(sb_ + g_off0, db_ + d_off0);                                  \
    gl_lds16(sb_ + g_off1, db_ + d_off1);                                  \
  }

#define LDF(AF, BF, ABP, BBP, S, AO, BO)                                   \
  _Pragma("unroll") for (int mt_ = 0; mt_ < 4; ++mt_)                      \
      AF[mt_] = *(const short8*)((ABP) + (S) * 16384 + (AO)[mt_]);         \
  _Pragma("unroll") for (int nt_ = 0; nt_ < 2; ++nt_)                      \
      BF[nt_] = *(const short8*)((BBP) + (S) * 16384 + (BO)[nt_]);

#define MFMA8_BODY(AF, BF)                                                 \
  __builtin_amdgcn_s_setprio(1);                                           \
  _Pragma("unroll") for (int mt_ = 0; mt_ < 4; ++mt_)                      \
      _Pragma("unroll") for (int nt_ = 0; nt_ < 2; ++nt_)                  \
          acc[mt_][nt_] = __builtin_amdgcn_mfma_f32_32x32x16_bf16(         \
              AF[mt_], BF[nt_], acc[mt_][nt_], 0, 0, 0);                   \
  __builtin_amdgcn_s_setprio(0);

#define MFMA8(AF, BF)                                                      \
  __builtin_amdgcn_sched_barrier(0);                                       \
  asm volatile("s_waitcnt lgkmcnt(6)" ::: "memory");                       \
  MFMA8_BODY(AF, BF)

#define MFMA8_LG0(AF, BF)                                                  \
  __builtin_amdgcn_sched_barrier(0);                                       \
  asm volatile("s_waitcnt lgkmcnt(0)" ::: "memory");                       \
  MFMA8_BODY(AF, BF)

__global__ __launch_bounds__(512, 2) void gemm_qkv(
    const short* __restrict__ A, const short* __restrict__ Bt,
    const float* __restrict__ bias, short* __restrict__ Qb,
    short* __restrict__ Kb, short* __restrict__ Vtb) {
  __shared__ __align__(16) short Asm[2][16384];  // 64KB
  __shared__ __align__(16) short Bsm[2][16384];  // 64KB
  const int tid = threadIdx.x;
  const int wv = tid >> 6;               // 0..7
  const int wr = wv >> 2, wc = wv & 3;   // 2M x 4N waves; wave tile 128x64
  const int ln32 = tid & 31, khalf = (tid >> 5) & 1;
  const int m0 = blockIdx.y * 256, n0 = blockIdx.x * 256;

  const int d_off0 = tid * 16, d_off1 = d_off0 + 8192;
  const int pa_st = ((tid & 3) - ((tid >> 3) & 3)) & 3;
  const size_t g_off0 = (size_t)(tid >> 2) * 1024 + (size_t)pa_st * 8;
  const size_t g_off1 = g_off0 + (size_t)128 * 1024;

  const int rot = (ln32 >> 1) & 3;
  const int slotE = (khalf + rot) & 3;
  const int slotO = (2 + khalf + rot) & 3;
  int aoffE[4], aoffO[4], boffE[2], boffO[2];
#pragma unroll
  for (int mt = 0; mt < 4; ++mt) {
    int r = (wr * 128 + mt * 32 + ln32) * 64;
    aoffE[mt] = r + slotE * 16;
    aoffO[mt] = r + slotO * 16;
  }
#pragma unroll
  for (int nt = 0; nt < 2; ++nt) {
    int r = (wc * 64 + nt * 32 + ln32) * 64;
    boffE[nt] = r + slotE * 16;
    boffO[nt] = r + slotO * 16;
  }

  const short* srcA = A + (size_t)m0 * 1024;
  const short* srcB = Bt + (size_t)n0 * 1024;

  f32x16 acc[4][2];
#pragma unroll
  for (int i = 0; i < 4; ++i)
#pragma unroll
    for (int j = 0; j < 2; ++j) acc[i][j] = (f32x16)(0.f);

  short8 af0[4], af1[4], bf0[2], bf1[2];

  STG(0, 0, srcA, Asm)
  STG(0, 0, srcB, Bsm)
  STG(0, 1, srcA, Asm)
  STG(0, 1, srcB, Bsm)
  STG(1, 0, srcA, Asm)
  STG(1, 0, srcB, Bsm)
  VMC(4);
  BARRIER();
  {
    const char* Ab0 = (const char*)Asm;
    const char* Bb0 = (const char*)Bsm;
    LDF(af0, bf0, Ab0, Bb0, 0, aoffE, boffE)
  }

  for (int kt = 0; kt < 16; ++kt) {
    const char* Ab = (const char*)Asm + ((kt & 1) << 15);
    const char* Bb = (const char*)Bsm + ((kt & 1) << 15);
    const char* An = (const char*)Asm + (((kt + 1) & 1) << 15);
    const char* Bn = (const char*)Bsm + (((kt + 1) & 1) << 15);
    // P0: consume set0 (kstep0); prefetch kstep1 -> set1
    LDF(af1, bf1, Ab, Bb, 0, aoffO, boffO)
    STG(kt + 1, 1, srcA, Asm)
    MFMA8(af0, bf0)
    // P1: consume set1 (kstep1); prefetch kstep2 -> set0
    LDF(af0, bf0, Ab, Bb, 1, aoffE, boffE)
    STG(kt + 1, 1, srcB, Bsm)
    MFMA8(af1, bf1)
    if (kt == 15) { VMC(0); } else { VMC(4); }
    BARRIER();
    // P2: consume set0 (kstep2); prefetch kstep3 -> set1
    LDF(af1, bf1, Ab, Bb, 1, aoffO, boffO)
    STG(kt + 2, 0, srcA, Asm)
    MFMA8(af0, bf0)
    // P3: consume set1 (kstep3); prefetch next tile kstep0 -> set0
    if (kt < 15) {
      LDF(af0, bf0, An, Bn, 0, aoffE, boffE)
      STG(kt + 2, 0, srcB, Bsm)
      MFMA8(af1, bf1)
      if (kt == 14) { VMC(0); } else { VMC(4); }
    } else {
      MFMA8_LG0(af1, bf1)
    }
    BARRIER();
  }

  // epilogue: 32x32 C/D map: col = lane&31 -> n; row = (a&3)+8*(a>>2)+4*khalf
  const int col = tid & 31;
  const int rhalf = khalf * 4;
#pragma unroll
  for (int i = 0; i < 4; ++i) {
#pragma unroll
    for (int j = 0; j < 2; ++j) {
      int n = n0 + wc * 64 + j * 32 + col;
      int n2 = n & 1023;
      int hh = n2 >> 6, d = n2 & 63;
      float bv = bias[n];
      int mb = m0 + wr * 128 + i * 32 + rhalf;
      int bb = mb >> 11;
      int bh = (bb << 4) + hh;
      if (n < 2048) {  // Q or K: [bh][t][d], scalar b16 stores
        const bool isq = n < 1024;
#pragma unroll
        for (int a = 0; a < 16; ++a) {
          int t = (mb + (a & 3) + 8 * (a >> 2)) & 2047;
          float o = acc[i][j][a] + bv;
          size_t idx = ((size_t)bh * 2048 + t) * 64 + d;
          if (isq)
            Qb[idx] = f2bf(o * 0.18033688f);
          else
            Kb[idx] = f2bf(o);
        }
      } else {  // V -> V4 fragment-tiled layout
        const int lnv = d & 15, mtv = d >> 4;
#pragma unroll
        for (int g = 0; g < 4; ++g) {
          int t0 = (mb + 8 * g) & 2047;  // t0 % 4 == 0
          int ktv = t0 >> 6, kbv = (t0 >> 4) & 3, qv = (t0 >> 2) & 3;
          short4v o;
#pragma unroll
          for (int r = 0; r < 4; ++r) o[r] = f2bf(acc[i][j][g * 4 + r] + bv);
          *(short4v*)&Vtb[(size_t)(((bh * 32 + ktv) * 4 + kbv) * 4 + mtv) * 256 +
                          (qv * 16 + lnv) * 4] = o;
        }
      }
    }
  }
}

// -------- flash attention: 1 wave/block, balanced, K-reg-prefetch (R21) ----
// bid -> (bh = bid&63, c = 63-(bid>>6)); each CU's 16 blocks step c by -4 ->
// equal per-CU work. K double-buffered in registers one iteration ahead;
// V4 (coalesced 512B-segment fragments) loaded at compute top. No LDS, no
// barriers. 4096 waves = 4/SIMD.

#define LOADK(DST, KT)                                                        \
  {                                                                           \
    const short* Kt_ = Kg + (size_t)(KT) * 4096;                              \
    _Pragma("unroll") for (int kb = 0; kb < 4; ++kb) {                        \
      DST[kb][0] = *(const short8*)(Kt_ + (kb * 16 + ln) * 64 + quad * 8);    \
      DST[kb][1] = *(const short8*)(Kt_ + (kb * 16 + ln) * 64 + 32 + quad * 8); \
    }                                                                         \
  }

#define FCOMPUTE(KS, KT)                                                      \
  {                                                                           \
    const short* Vt_ = V4 + (size_t)(KT) * 4096;                              \
    short4v vr[4][4];                                                         \
    _Pragma("unroll") for (int kb = 0; kb < 4; ++kb)                          \
        _Pragma("unroll") for (int mt = 0; mt < 4; ++mt)                      \
            vr[kb][mt] =                                                      \
                *(const short4v*)(Vt_ + (kb * 4 + mt) * 256 + lane * 4);      \
    f32x4 St[2][4];                                                           \
    _Pragma("unroll") for (int h = 0; h < 2; ++h)                             \
        _Pragma("unroll") for (int kb = 0; kb < 4; ++kb)                      \
            St[h][kb] = (f32x4){0.f, 0.f, 0.f, 0.f};                          \
    __builtin_amdgcn_s_setprio(1);                                            \
    _Pragma("unroll") for (int kb = 0; kb < 4; ++kb)                          \
        _Pragma("unroll") for (int h = 0; h < 2; ++h) {                       \
          St[h][kb] = __builtin_amdgcn_mfma_f32_16x16x32_bf16(                \
              KS[kb][0], qf[h][0], St[h][kb], 0, 0, 0);                       \
          St[h][kb] = __builtin_amdgcn_mfma_f32_16x16x32_bf16(                \
              KS[kb][1], qf[h][1], St[h][kb], 0, 0, 0);                       \
        }                                                                     \
    __builtin_amdgcn_s_setprio(0);                                            \
    short4v pf[2][4];                                                         \
    _Pragma("unroll") for (int h = 0; h < 2; ++h) {                           \
      float lp0 = 0.f, lp1 = 0.f;                                             \
      if ((KT)*64 + 63 <= qbase + h * 16) {                                   \
        _Pragma("unroll") for (int kb = 0; kb < 4; ++kb) {                    \
          float p[4];                                                         \
          _Pragma("unroll") for (int r = 0; r < 4; ++r)                       \
              p[r] = __builtin_amdgcn_exp2f(St[h][kb][r]);                    \
          lp0 += p[0] + p[2];                                                 \
          lp1 += p[1] + p[3];                                                 \
          union { __hip_bfloat162 b2; unsigned u; } w0, w1;                   \
          w0.b2 = __float22bfloat162_rn(make_float2(p[0], p[1]));             \
          w1.b2 = __float22bfloat162_rn(make_float2(p[2], p[3]));             \
          union { short4v s4; unsigned u2[2]; } mm;                           \
          mm.u2[0] = w0.u; mm.u2[1] = w1.u;                                   \
          pf[h][kb] = mm.s4;                                                  \
        }                                                                     \
      } else {                                                                \
        const int qg = qbase + h * 16 + ln;                                   \
        _Pragma("unroll") for (int kb = 0; kb < 4; ++kb) {                    \
          float p[4];                                                         \
          _Pragma("unroll") for (int r = 0; r < 4; ++r) {                     \
            int key = (KT)*64 + kb * 16 + quad * 4 + r;                       \
            float s = (key <= qg) ? St[h][kb][r] : -1e30f;                    \
            p[r] = __builtin_amdgcn_exp2f(s);                                 \
          }                                                                   \
          lp0 += p[0] + p[2];                                                 \
          lp1 += p[1] + p[3];                                                 \
          union { __hip_bfloat162 b2; unsigned u; } w0, w1;                   \
          w0.b2 = __float22bfloat162_rn(make_float2(p[0], p[1]));             \
          w1.b2 = __float22bfloat162_rn(make_float2(p[2], p[3]));             \
          union { short4v s4; unsigned u2[2]; } mm;                           \
          mm.u2[0] = w0.u; mm.u2[1] = w1.u;                                   \
          pf[h][kb] = mm.s4;                                                  \
        }                                                                     \
      }                                                                       \
      lpart[h] += lp0 + lp1;                                                  \
    }                                                                         \
    __builtin_amdgcn_s_setprio(1);                                            \
    _Pragma("unroll") for (int kb = 0; kb < 4; ++kb)                          \
        _Pragma("unroll") for (int mt = 0; mt < 4; ++mt)                      \
            _Pragma("unroll") for (int h = 0; h < 2; ++h)                     \
                Oacc[h][mt] = __builtin_amdgcn_mfma_f32_16x16x16bf16_1k(      \
                    vr[kb][mt], pf[h][kb], Oacc[h][mt], 0, 0, 0);             \
    __builtin_amdgcn_s_setprio(0);                                            \
  }

__global__ __launch_bounds__(64, 4) void flash_attn(
    const short* __restrict__ Qg_, const short* __restrict__ Kg_,
    const short* __restrict__ V4_, short* __restrict__ Ob) {
  const int tid = threadIdx.x;
  const int ln = tid & 15, quad = (tid >> 4) & 3;
  const int lane = tid;
  const int bh = blockIdx.x & 63;
  const int c = 63 - (blockIdx.x >> 6);  // longest chunks first
  const int qbase = c * 32;
  const int nkt = (c >> 1) + 1;
  const short* Qg = Qg_ + (size_t)bh * 2048 * 64;
  const short* Kg = Kg_ + (size_t)bh * 2048 * 64;
  const short* V4 = V4_ + (size_t)bh * 131072;
  const int bb = bh >> 4, hh = bh & 15;

  short8 qf[2][2];
#pragma unroll
  for (int h = 0; h < 2; ++h)
#pragma unroll
    for (int ch = 0; ch < 2; ++ch)
      qf[h][ch] = *(const short8*)(Qg + (size_t)(qbase + h * 16 + ln) * 64 +
                                   ch * 32 + quad * 8);

  f32x4 Oacc[2][4];
#pragma unroll
  for (int h = 0; h < 2; ++h)
#pragma unroll
    for (int mt = 0; mt < 4; ++mt) Oacc[h][mt] = (f32x4){0.f, 0.f, 0.f, 0.f};
  float lpart[2] = {0.f, 0.f};

  short8 kA[4][2], kB[4][2];
  LOADK(kA, 0)
  int kt = 0;
  while (true) {
    if (kt + 1 < nkt) LOADK(kB, kt + 1)
    FCOMPUTE(kA, kt)
    ++kt;
    if (kt == nkt) break;
    if (kt + 1 < nkt) LOADK(kA, kt + 1)
    FCOMPUTE(kB, kt)
    ++kt;
    if (kt == nkt) break;
  }

#pragma unroll
  for (int h = 0; h < 2; ++h) {
    float l = lpart[h];
    l += __shfl_xor(l, 16);
    l += __shfl_xor(l, 32);
    float rl = 1.0f / l;
    int t = qbase + h * 16 + ln;
#pragma unroll
    for (int mt = 0; mt < 4; ++mt) {
      short4v o;
#pragma unroll
      for (int r = 0; r < 4; ++r) o[r] = f2bf(Oacc[h][mt][r] * rl);
      *(short4v*)(Ob + ((size_t)(bb * 2048 + t)) * 1024 + hh * 64 + mt * 16 +
                  quad * 4) = o;
    }
  }
}

// ---------------- launcher ----------------

extern "C" void kernel_launch(void* const* d_in, const int* in_sizes, int n_in,
                              void* d_out, int out_size, void* d_ws, size_t ws_size,
                              hipStream_t stream) {
  const float* x      = (const float*)d_in[0];
  const float* w_attn = (const float*)d_in[1];
  const float* b_attn = (const float*)d_in[2];
  const float* w_proj = (const float*)d_in[3];
  const float* b_proj = (const float*)d_in[4];
  float* out = (float*)d_out;
  char* ws = (char*)d_ws;

  short* xb  = (short*)(ws);
  short* wat = (short*)(ws + 16777216);
  short* wpt = (short*)(ws + 23068672);
  short* Qb  = (short*)(ws + 25165824);
  short* Kb  = (short*)(ws + 41943040);
  short* Vtb = (short*)(ws + 58720256);
  short* Ob  = (short*)(ws + 75497472);

  prep<<<12288, 256, 0, stream>>>(x, w_attn, w_proj, xb, wat, wpt);
  gemm_qkv<<<dim3(12, 32), 512, 0, stream>>>(xb, wat, b_attn, Qb, Kb, Vtb);
  flash_attn<<<4096, 64, 0, stream>>>(Qb, Kb, Vtb, Ob);
  gemm_proj<<<dim3(8, 64), 256, 0, stream>>>(Ob, wpt, b_proj, out);
}

// Round 11
// 294.518 us; speedup vs baseline: 1.7770x; 1.7770x over previous
//
#include <hip/hip_runtime.h>
#include <hip/hip_bf16.h>

// CausalSelfAttention: B=4 T=2048 C=1024 H=16 D=64
// ws layout (bytes):
//   xb   @ 0         : x as bf16           [8192][1024]   16 MB
//   wat  @ 16777216  : w_attn^T bf16       [3072][1024]    6 MB
//   wpt  @ 23068672  : w_proj^T bf16       [1024][1024]    2 MB
//   Qb   @ 25165824  : Q bf16 (pre-scaled by 0.125*log2e) [B,H,T,D] 16 MB
//   Kb   @ 41943040  : K bf16  [B,H,T,D]                  16 MB
//   V4   @ 58720256  : V fragment-tiled bf16 [bh][kt][kb][mt][lane][4] 16 MB
//   Ob   @ 75497472  : attn out bf16 [8192][1024]         16 MB
//
// R22: R21 post-mortem — FETCH 500MB + WRITE 1010MB/dispatch = SCRATCH SPILL
// (kA/kB+vr demanded ~170 VGPR under the launch_bounds(64,4) 128 cap); the
// balance fix was masked. R22 = R20's lean compute body (VGPR 64, no spill:
// K and V fragments loaded per-kb INSIDE the QK/PV loops, 8 VGPR transient;
// co-resident waves are the latency hiding, not private buffers) + R21's
// balanced single-wave mapping (4096 x 64thr, bh=bid&63, c=63-(bid>>6):
// per-CU work equal by construction, longest first). Register audit ~85.
// qkv = R16 (80.8us) + V4 epilogue; proj unchanged.

typedef float f32x4 __attribute__((ext_vector_type(4)));
typedef float f32x16 __attribute__((ext_vector_type(16)));
typedef short short8 __attribute__((ext_vector_type(8)));
typedef short short4v __attribute__((ext_vector_type(4)));

__device__ __forceinline__ short f2bf(float f) {
  union { __hip_bfloat16 h; short s; } u;
  u.h = __float2bfloat16(f);
  return u.s;
}

__device__ __forceinline__ void gl_lds16(const void* g, void* l) {
  __builtin_amdgcn_global_load_lds(
      (const __attribute__((address_space(1))) void*)g,
      (__attribute__((address_space(3))) void*)l, 16, 0, 0);
}

// ---------------- fused prep: x cvt + w_attn^T + w_proj^T -------------------
__global__ void prep(const float* __restrict__ x, const float* __restrict__ wa,
                     const float* __restrict__ wp, short* __restrict__ xb,
                     short* __restrict__ wat, short* __restrict__ wpt) {
  const int bid = blockIdx.x, tid = threadIdx.x;
  if (bid < 8192) {
    int i = (bid * 256 + tid) * 4;
    float4 v = *(const float4*)(x + i);
    short4v o;
    o[0] = f2bf(v.x); o[1] = f2bf(v.y); o[2] = f2bf(v.z); o[3] = f2bf(v.w);
    *(short4v*)(xb + i) = o;
    return;
  }
  __shared__ float tile[32][33];
  const float* in;
  short* out;
  int N, bx, by;
  if (bid < 11264) {
    int t = bid - 8192;
    in = wa; out = wat; N = 3072; bx = t % 96; by = t / 96;
  } else {
    int t = bid - 11264;
    in = wp; out = wpt; N = 1024; bx = t & 31; by = t >> 5;
  }
  int tx = tid & 31, ty = tid >> 5;  // 32 x 8
  int x0 = bx * 32, y0 = by * 32;
#pragma unroll
  for (int i = 0; i < 32; i += 8)
    tile[ty + i][tx] = in[(size_t)(y0 + ty + i) * N + x0 + tx];
  __syncthreads();
#pragma unroll
  for (int i = 0; i < 32; i += 8)
    out[(size_t)(x0 + ty + i) * 1024 + y0 + tx] = f2bf(tile[tx][ty + i]);
}

// ------ proj GEMM core: 128x128, BK=32, 4 waves, DBUF LDS, 1 barrier/kt ----
#define GEMM_BODY(A_, Bt_)                                                        \
  __shared__ __align__(16) short As[2][128 * 32];                                 \
  __shared__ __align__(16) short Bs[2][128 * 32];                                 \
  const int tid = threadIdx.x;                                                    \
  const int wv = tid >> 6;                                                        \
  const int wr = wv >> 1, wc = wv & 1;                                            \
  const int col = tid & 31, khalf = (tid >> 5) & 1;                               \
  const int m0 = blockIdx.y * 128, n0 = blockIdx.x * 128;                         \
  const int cc0 = tid, cc1 = tid + 256;                                           \
  const int row0 = cc0 >> 2, part0 = ((cc0 & 3) - ((cc0 >> 3) & 3)) & 3;          \
  const int row1 = cc1 >> 2, part1 = ((cc1 & 3) - ((cc1 >> 3) & 3)) & 3;          \
  const size_t ga0 = (size_t)(m0 + row0) * 1024 + part0 * 8;                      \
  const size_t ga1 = (size_t)(m0 + row1) * 1024 + part1 * 8;                      \
  const size_t gb0 = (size_t)(n0 + row0) * 1024 + part0 * 8;                      \
  const size_t gb1 = (size_t)(n0 + row1) * 1024 + part1 * 8;                      \
  f32x16 acc[2][2];                                                               \
  _Pragma("unroll") for (int i = 0; i < 2; ++i)                                   \
      _Pragma("unroll") for (int j = 0; j < 2; ++j)                               \
          acc[i][j] = (f32x16)(0.f);                                              \
  gl_lds16(A_ + ga0, (char*)As[0] + cc0 * 16);                                    \
  gl_lds16(A_ + ga1, (char*)As[0] + cc1 * 16);                                    \
  gl_lds16(Bt_ + gb0, (char*)Bs[0] + cc0 * 16);                                   \
  gl_lds16(Bt_ + gb1, (char*)Bs[0] + cc1 * 16);                                   \
  __syncthreads();                                                                \
  for (int kt = 0; kt < 32; ++kt) {                                               \
    if (kt + 1 < 32) {                                                            \
      const int k0 = (kt + 1) * 32;                                               \
      char* Ad = (char*)As[(kt + 1) & 1];                                         \
      char* Bd = (char*)Bs[(kt + 1) & 1];                                         \
      gl_lds16(A_ + ga0 + k0, Ad + cc0 * 16);                                     \
      gl_lds16(A_ + ga1 + k0, Ad + cc1 * 16);                                     \
      gl_lds16(Bt_ + gb0 + k0, Bd + cc0 * 16);                                    \
      gl_lds16(Bt_ + gb1 + k0, Bd + cc1 * 16);                                    \
    }                                                                             \
    const short* Ac = As[kt & 1];                                                 \
    const short* Bc = Bs[kt & 1];                                                 \
    short8 af[2][2], bf[2][2];                                                    \
    _Pragma("unroll") for (int i = 0; i < 2; ++i)                                 \
        _Pragma("unroll") for (int s = 0; s < 2; ++s) {                           \
          int pa = s * 2 + khalf;                                                 \
          int ra = wr * 64 + i * 32 + col;                                        \
          int rb = wc * 64 + i * 32 + col;                                        \
          af[i][s] = *(const short8*)&Ac[(ra * 4 + ((pa + (ra >> 1)) & 3)) * 8];  \
          bf[i][s] = *(const short8*)&Bc[(rb * 4 + ((pa + (rb >> 1)) & 3)) * 8];  \
        }                                                                         \
    _Pragma("unroll") for (int s = 0; s < 2; ++s)                                 \
        _Pragma("unroll") for (int i = 0; i < 2; ++i)                             \
            _Pragma("unroll") for (int j = 0; j < 2; ++j)                         \
                acc[i][j] = __builtin_amdgcn_mfma_f32_32x32x16_bf16(              \
                    af[i][s], bf[j][s], acc[i][j], 0, 0, 0);                      \
    __syncthreads();                                                              \
  }

__global__ __launch_bounds__(256, 2) void gemm_proj(
    const short* __restrict__ A, const short* __restrict__ Bt,
    const float* __restrict__ bias, float* __restrict__ out) {
  GEMM_BODY(A, Bt)
  const int rhalf = khalf * 4;
#pragma unroll
  for (int i = 0; i < 2; ++i) {
#pragma unroll
    for (int j = 0; j < 2; ++j) {
      int n = n0 + wc * 64 + j * 32 + col;
      float bv = bias[n];
      int mb = m0 + wr * 64 + i * 32 + rhalf;
#pragma unroll
      for (int a = 0; a < 16; ++a) {
        int m = mb + (a & 3) + 8 * (a >> 2);
        out[(size_t)m * 1024 + n] = acc[i][j][a] + bv;
      }
    }
  }
}

// ------------- QKV GEMM: R16 (256x256, BK=64, reg-prefetch, 2 barriers/kt) -
#define BARRIER() asm volatile("s_barrier" ::: "memory")
#define VMC(N) asm volatile("s_waitcnt vmcnt(" #N ")" ::: "memory")

#define STG(KT, S, SRC, LB)                                                \
  if ((KT) < 16) {                                                         \
    char* db_ = (char*)(LB) + (((KT) & 1) ? 32768 : 0) + ((S) * 16384);    \
    const short* sb_ = (SRC) + (KT) * 64 + (S) * 32;                       \
    gl_lds16(sb_ + g_off0, db_ + d_off0);                                  \
    gl_lds16(sb_ + g_off1, db_ + d_off1);                                  \
  }

#define LDF(AF, BF, ABP, BBP, S, AO, BO)                                   \
  _Pragma("unroll") for (int mt_ = 0; mt_ < 4; ++mt_)                      \
      AF[mt_] = *(const short8*)((ABP) + (S) * 16384 + (AO)[mt_]);         \
  _Pragma("unroll") for (int nt_ = 0; nt_ < 2; ++nt_)                      \
      BF[nt_] = *(const short8*)((BBP) + (S) * 16384 + (BO)[nt_]);

#define MFMA8_BODY(AF, BF)                                                 \
  __builtin_amdgcn_s_setprio(1);                                           \
  _Pragma("unroll") for (int mt_ = 0; mt_ < 4; ++mt_)                      \
      _Pragma("unroll") for (int nt_ = 0; nt_ < 2; ++nt_)                  \
          acc[mt_][nt_] = __builtin_amdgcn_mfma_f32_32x32x16_bf16(         \
              AF[mt_], BF[nt_], acc[mt_][nt_], 0, 0, 0);                   \
  __builtin_amdgcn_s_setprio(0);

#define MFMA8(AF, BF)                                                      \
  __builtin_amdgcn_sched_barrier(0);                                       \
  asm volatile("s_waitcnt lgkmcnt(6)" ::: "memory");                       \
  MFMA8_BODY(AF, BF)

#define MFMA8_LG0(AF, BF)                                                  \
  __builtin_amdgcn_sched_barrier(0);                                       \
  asm volatile("s_waitcnt lgkmcnt(0)" ::: "memory");                       \
  MFMA8_BODY(AF, BF)

__global__ __launch_bounds__(512, 2) void gemm_qkv(
    const short* __restrict__ A, const short* __restrict__ Bt,
    const float* __restrict__ bias, short* __restrict__ Qb,
    short* __restrict__ Kb, short* __restrict__ Vtb) {
  __shared__ __align__(16) short Asm[2][16384];  // 64KB
  __shared__ __align__(16) short Bsm[2][16384];  // 64KB
  const int tid = threadIdx.x;
  const int wv = tid >> 6;               // 0..7
  const int wr = wv >> 2, wc = wv & 3;   // 2M x 4N waves; wave tile 128x64
  const int ln32 = tid & 31, khalf = (tid >> 5) & 1;
  const int m0 = blockIdx.y * 256, n0 = blockIdx.x * 256;

  const int d_off0 = tid * 16, d_off1 = d_off0 + 8192;
  const int pa_st = ((tid & 3) - ((tid >> 3) & 3)) & 3;
  const size_t g_off0 = (size_t)(tid >> 2) * 1024 + (size_t)pa_st * 8;
  const size_t g_off1 = g_off0 + (size_t)128 * 1024;

  const int rot = (ln32 >> 1) & 3;
  const int slotE = (khalf + rot) & 3;
  const int slotO = (2 + khalf + rot) & 3;
  int aoffE[4], aoffO[4], boffE[2], boffO[2];
#pragma unroll
  for (int mt = 0; mt < 4; ++mt) {
    int r = (wr * 128 + mt * 32 + ln32) * 64;
    aoffE[mt] = r + slotE * 16;
    aoffO[mt] = r + slotO * 16;
  }
#pragma unroll
  for (int nt = 0; nt < 2; ++nt) {
    int r = (wc * 64 + nt * 32 + ln32) * 64;
    boffE[nt] = r + slotE * 16;
    boffO[nt] = r + slotO * 16;
  }

  const short* srcA = A + (size_t)m0 * 1024;
  const short* srcB = Bt + (size_t)n0 * 1024;

  f32x16 acc[4][2];
#pragma unroll
  for (int i = 0; i < 4; ++i)
#pragma unroll
    for (int j = 0; j < 2; ++j) acc[i][j] = (f32x16)(0.f);

  short8 af0[4], af1[4], bf0[2], bf1[2];

  STG(0, 0, srcA, Asm)
  STG(0, 0, srcB, Bsm)
  STG(0, 1, srcA, Asm)
  STG(0, 1, srcB, Bsm)
  STG(1, 0, srcA, Asm)
  STG(1, 0, srcB, Bsm)
  VMC(4);
  BARRIER();
  {
    const char* Ab0 = (const char*)Asm;
    const char* Bb0 = (const char*)Bsm;
    LDF(af0, bf0, Ab0, Bb0, 0, aoffE, boffE)
  }

  for (int kt = 0; kt < 16; ++kt) {
    const char* Ab = (const char*)Asm + ((kt & 1) << 15);
    const char* Bb = (const char*)Bsm + ((kt & 1) << 15);
    const char* An = (const char*)Asm + (((kt + 1) & 1) << 15);
    const char* Bn = (const char*)Bsm + (((kt + 1) & 1) << 15);
    // P0: consume set0 (kstep0); prefetch kstep1 -> set1
    LDF(af1, bf1, Ab, Bb, 0, aoffO, boffO)
    STG(kt + 1, 1, srcA, Asm)
    MFMA8(af0, bf0)
    // P1: consume set1 (kstep1); prefetch kstep2 -> set0
    LDF(af0, bf0, Ab, Bb, 1, aoffE, boffE)
    STG(kt + 1, 1, srcB, Bsm)
    MFMA8(af1, bf1)
    if (kt == 15) { VMC(0); } else { VMC(4); }
    BARRIER();
    // P2: consume set0 (kstep2); prefetch kstep3 -> set1
    LDF(af1, bf1, Ab, Bb, 1, aoffO, boffO)
    STG(kt + 2, 0, srcA, Asm)
    MFMA8(af0, bf0)
    // P3: consume set1 (kstep3); prefetch next tile kstep0 -> set0
    if (kt < 15) {
      LDF(af0, bf0, An, Bn, 0, aoffE, boffE)
      STG(kt + 2, 0, srcB, Bsm)
      MFMA8(af1, bf1)
      if (kt == 14) { VMC(0); } else { VMC(4); }
    } else {
      MFMA8_LG0(af1, bf1)
    }
    BARRIER();
  }

  // epilogue: 32x32 C/D map: col = lane&31 -> n; row = (a&3)+8*(a>>2)+4*khalf
  const int col = tid & 31;
  const int rhalf = khalf * 4;
#pragma unroll
  for (int i = 0; i < 4; ++i) {
#pragma unroll
    for (int j = 0; j < 2; ++j) {
      int n = n0 + wc * 64 + j * 32 + col;
      int n2 = n & 1023;
      int hh = n2 >> 6, d = n2 & 63;
      float bv = bias[n];
      int mb = m0 + wr * 128 + i * 32 + rhalf;
      int bb = mb >> 11;
      int bh = (bb << 4) + hh;
      if (n < 2048) {  // Q or K: [bh][t][d], scalar b16 stores
        const bool isq = n < 1024;
#pragma unroll
        for (int a = 0; a < 16; ++a) {
          int t = (mb + (a & 3) + 8 * (a >> 2)) & 2047;
          float o = acc[i][j][a] + bv;
          size_t idx = ((size_t)bh * 2048 + t) * 64 + d;
          if (isq)
            Qb[idx] = f2bf(o * 0.18033688f);
          else
            Kb[idx] = f2bf(o);
        }
      } else {  // V -> V4 fragment-tiled layout
        const int lnv = d & 15, mtv = d >> 4;
#pragma unroll
        for (int g = 0; g < 4; ++g) {
          int t0 = (mb + 8 * g) & 2047;  // t0 % 4 == 0
          int ktv = t0 >> 6, kbv = (t0 >> 4) & 3, qv = (t0 >> 2) & 3;
          short4v o;
#pragma unroll
          for (int r = 0; r < 4; ++r) o[r] = f2bf(acc[i][j][g * 4 + r] + bv);
          *(short4v*)&Vtb[(size_t)(((bh * 32 + ktv) * 4 + kbv) * 4 + mtv) * 256 +
                          (qv * 16 + lnv) * 4] = o;
        }
      }
    }
  }
}

// -------- flash attention: 1 wave/block, balanced, lean registers (R22) ----
// bid -> (bh = bid&63, c = 63-(bid>>6)); each CU's 16 blocks step c by -4 ->
// equal per-CU work, longest chunks first. K fragments loaded per-kb inside
// the QK loop; V4 fragments (coalesced 512B segments) per-kb inside the PV
// loop — 8 VGPR transient each; co-resident waves (4/SIMD) hide latency.
// No LDS, no barriers. Register audit ~85 < 128 cap.
__global__ __launch_bounds__(64, 4) void flash_attn(
    const short* __restrict__ Qg_, const short* __restrict__ Kg_,
    const short* __restrict__ V4_, short* __restrict__ Ob) {
  const int tid = threadIdx.x;
  const int ln = tid & 15, quad = (tid >> 4) & 3;
  const int lane = tid;
  const int bh = blockIdx.x & 63;
  const int c = 63 - (blockIdx.x >> 6);  // longest chunks first
  const int qbase = c * 32;
  const int nkt = (c >> 1) + 1;
  const short* Qg = Qg_ + (size_t)bh * 2048 * 64;
  const short* Kg = Kg_ + (size_t)bh * 2048 * 64;
  const short* V4 = V4_ + (size_t)bh * 131072;
  const int bb = bh >> 4, hh = bh & 15;

  short8 qf[2][2];
#pragma unroll
  for (int h = 0; h < 2; ++h)
#pragma unroll
    for (int ch = 0; ch < 2; ++ch)
      qf[h][ch] = *(const short8*)(Qg + (size_t)(qbase + h * 16 + ln) * 64 +
                                   ch * 32 + quad * 8);

  f32x4 Oacc[2][4];
#pragma unroll
  for (int h = 0; h < 2; ++h)
#pragma unroll
    for (int mt = 0; mt < 4; ++mt) Oacc[h][mt] = (f32x4){0.f, 0.f, 0.f, 0.f};
  float lpart[2] = {0.f, 0.f};

  for (int kt = 0; kt < nkt; ++kt) {
    const short* Kt = Kg + (size_t)kt * 4096;
    const short* Vt = V4 + (size_t)kt * 4096;

    f32x4 St[2][4];
#pragma unroll
    for (int h = 0; h < 2; ++h)
#pragma unroll
      for (int kb = 0; kb < 4; ++kb) St[h][kb] = (f32x4){0.f, 0.f, 0.f, 0.f};
    __builtin_amdgcn_s_setprio(1);
#pragma unroll
    for (int kb = 0; kb < 4; ++kb) {
      short8 ka0 = *(const short8*)(Kt + (kb * 16 + ln) * 64 + quad * 8);
      short8 ka1 = *(const short8*)(Kt + (kb * 16 + ln) * 64 + 32 + quad * 8);
#pragma unroll
      for (int h = 0; h < 2; ++h) {
        St[h][kb] = __builtin_amdgcn_mfma_f32_16x16x32_bf16(ka0, qf[h][0],
                                                            St[h][kb], 0, 0, 0);
        St[h][kb] = __builtin_amdgcn_mfma_f32_16x16x32_bf16(ka1, qf[h][1],
                                                            St[h][kb], 0, 0, 0);
      }
    }
    __builtin_amdgcn_s_setprio(0);

    short4v pf[2][4];
#pragma unroll
    for (int h = 0; h < 2; ++h) {
      float lp0 = 0.f, lp1 = 0.f;
      if (kt * 64 + 63 <= qbase + h * 16) {  // fully unmasked
#pragma unroll
        for (int kb = 0; kb < 4; ++kb) {
          float p[4];
#pragma unroll
          for (int r = 0; r < 4; ++r)
            p[r] = __builtin_amdgcn_exp2f(St[h][kb][r]);
          lp0 += p[0] + p[2];
          lp1 += p[1] + p[3];
          union { __hip_bfloat162 b2; unsigned u; } w0, w1;
          w0.b2 = __float22bfloat162_rn(make_float2(p[0], p[1]));
          w1.b2 = __float22bfloat162_rn(make_float2(p[2], p[3]));
          union { short4v s4; unsigned u2[2]; } mm;
          mm.u2[0] = w0.u; mm.u2[1] = w1.u;
          pf[h][kb] = mm.s4;
        }
      } else {  // diagonal tile: per-element causal mask
        const int qg = qbase + h * 16 + ln;
#pragma unroll
        for (int kb = 0; kb < 4; ++kb) {
          float p[4];
#pragma unroll
          for (int r = 0; r < 4; ++r) {
            int key = kt * 64 + kb * 16 + quad * 4 + r;
            float s = (key <= qg) ? St[h][kb][r] : -1e30f;
            p[r] = __builtin_amdgcn_exp2f(s);
          }
          lp0 += p[0] + p[2];
          lp1 += p[1] + p[3];
          union { __hip_bfloat162 b2; unsigned u; } w0, w1;
          w0.b2 = __float22bfloat162_rn(make_float2(p[0], p[1]));
          w1.b2 = __float22bfloat162_rn(make_float2(p[2], p[3]));
          union { short4v s4; unsigned u2[2]; } mm;
          mm.u2[0] = w0.u; mm.u2[1] = w1.u;
          pf[h][kb] = mm.s4;
        }
      }
      lpart[h] += lp0 + lp1;
    }

    __builtin_amdgcn_s_setprio(1);
#pragma unroll
    for (int kb = 0; kb < 4; ++kb) {
#pragma unroll
      for (int mt = 0; mt < 4; ++mt) {
        short4v va = *(const short4v*)(Vt + (kb * 4 + mt) * 256 + lane * 4);
#pragma unroll
        for (int h = 0; h < 2; ++h)
          Oacc[h][mt] = __builtin_amdgcn_mfma_f32_16x16x16bf16_1k(
              va, pf[h][kb], Oacc[h][mt], 0, 0, 0);
      }
    }
    __builtin_amdgcn_s_setprio(0);
  }

#pragma unroll
  for (int h = 0; h < 2; ++h) {
    float l = lpart[h];
    l += __shfl_xor(l, 16);
    l += __shfl_xor(l, 32);
    float rl = 1.0f / l;
    int t = qbase + h * 16 + ln;
#pragma unroll
    for (int mt = 0; mt < 4; ++mt) {
      short4v o;
#pragma unroll
      for (int r = 0; r < 4; ++r) o[r] = f2bf(Oacc[h][mt][r] * rl);
      *(short4v*)(Ob + ((size_t)(bb * 2048 + t)) * 1024 + hh * 64 + mt * 16 +
                  quad * 4) = o;
    }
  }
}

// ---------------- launcher ----------------

extern "C" void kernel_launch(void* const* d_in, const int* in_sizes, int n_in,
                              void* d_out, int out_size, void* d_ws, size_t ws_size,
                              hipStream_t stream) {
  const float* x      = (const float*)d_in[0];
  const float* w_attn = (const float*)d_in[1];
  const float* b_attn = (const float*)d_in[2];
  const float* w_proj = (const float*)d_in[3];
  const float* b_proj = (const float*)d_in[4];
  float* out = (float*)d_out;
  char* ws = (char*)d_ws;

  short* xb  = (short*)(ws);
  short* wat = (short*)(ws + 16777216);
  short* wpt = (short*)(ws + 23068672);
  short* Qb  = (short*)(ws + 25165824);
  short* Kb  = (short*)(ws + 41943040);
  short* Vtb = (short*)(ws + 58720256);
  short* Ob  = (short*)(ws + 75497472);

  prep<<<12288, 256, 0, stream>>>(x, w_attn, w_proj, xb, wat, wpt);
  gemm_qkv<<<dim3(12, 32), 512, 0, stream>>>(xb, wat, b_attn, Qb, Kb, Vtb);
  flash_attn<<<4096, 64, 0, stream>>>(Qb, Kb, Vtb, Ob);
  gemm_proj<<<dim3(8, 64), 256, 0, stream>>>(Ob, wpt, b_proj, out);
}